// Round 17
// baseline (219.852 us; speedup 1.0000x reference)
//
#include <hip/hip_runtime.h>
#include <hip/hip_bf16.h>
#include <hip/hip_fp16.h>

// INPUTS/OUTPUT ARE FLOAT32 (R1/R3/R4 NaN'd reading them as bf16).
// PERF NOTES:
//  - R5: forced low VGPR budget -> scratch spills, 2.6x slower.
//  - R11/R13/R16: three different inner-loop mixes all = 145.7 us edge ->
//    instruction floor reached; model: single exec port, trans ~12cyc x65 +
//    VALU ~224cyc = 1004 busy of 1366 cyc/m-step (= measured 77% VALUBusy).
//    Remaining ~360 cyc/m-step = chain bubbles, needs more resident waves.
//  - R12/R14: occupancy insensitive to LDS size and block count.
//  - R17 probe: 512-thread blocks (8 waves, n-range 128, 512 blocks). If the
//    residency cap is per-BLOCK (~2/CU), waves/CU doubles.

#define NTOT 2048
#define MTOT 2048
#define MSPLIT 32
#define MCHUNK 64    // per-block m range: single staging chunk
#define BLOCKT 512   // threads per block (8 waves)
#define NBLOCK 128   // n-rows per block (8 waves x 16)
#define NODE_ROWS 4  // rows per node block (1 per wave)

typedef _Float16 f16x8 __attribute__((ext_vector_type(8)));
typedef float f32x4  __attribute__((ext_vector_type(4)));
typedef float f32x2  __attribute__((ext_vector_type(2)));
typedef int   i32x4  __attribute__((ext_vector_type(4)));

// exp(x) = 2^(x*log2e); sigmoid(x) = 1/(1+2^(-x*log2e))
#define NL2E (-1.4426950408889634f)
// exp(-d2/5) = 2^(d2 * -log2e/5)
#define C1E  (-0.2885390081777927f)

__device__ __forceinline__ float fast_exp2(float x) {
#if __has_builtin(__builtin_amdgcn_exp2f)
  return __builtin_amdgcn_exp2f(x);
#else
  return __exp2f(x);
#endif
}
__device__ __forceinline__ float fast_rcp(float x) {
#if __has_builtin(__builtin_amdgcn_rcpf)
  return __builtin_amdgcn_rcpf(x);
#else
  return 1.0f / x;
#endif
}
__device__ __forceinline__ float fast_rsq(float x) {
#if __has_builtin(__builtin_amdgcn_rsqf)
  return __builtin_amdgcn_rsqf(x);
#else
  return rsqrtf(x);
#endif
}
__device__ __forceinline__ f32x2 pk_fma(f32x2 a, f32x2 b, f32x2 c) {
  return __builtin_elementwise_fma(a, b, c);
}

// pack two f32 -> two f16 (RTZ) in one u32 via v_cvt_pkrtz_f16_f32 (1 instr).
__device__ __forceinline__ unsigned pack_f16_rtz(float lo, float hi) {
#if __has_builtin(__builtin_amdgcn_cvt_pkrtz)
  auto p = __builtin_amdgcn_cvt_pkrtz(lo, hi);  // __fp16 ext_vector(2)
  return __builtin_bit_cast(unsigned, p);
#else
  union { _Float16 h; unsigned short u; } a, b;
  a.h = (_Float16)lo; b.h = (_Float16)hi;
  return (unsigned)a.u | ((unsigned)b.u << 16);
#endif
}

// ---------------------------------------------------------------------------
// Edge phase: 512-thread blocks, 8 waves x 16 n-rows; loop over 64-m chunk.
// dist-arg via d2 expansion; layer1+silu packed f32; A-frags via cvt_pkrtz;
// mfma_16x16x32_f16; sigmoid f32; atomicAdd partials.
// Grid: (NTOT/NBLOCK) * MSPLIT = 512 blocks of 512.
// ---------------------------------------------------------------------------
__global__ __launch_bounds__(BLOCKT)
void edge_kernel(const float* __restrict__ h_l,
                 const float* __restrict__ x_l,
                 const float* __restrict__ h_r,
                 const float* __restrict__ x_r,
                 const float* __restrict__ W1,
                 const float* __restrict__ b1,
                 const float* __restrict__ W2,
                 const float* __restrict__ b2,
                 float* __restrict__ num_g,
                 float* __restrict__ den_g) {
  // hrT[ms][l15*4 + c] = h_r[m][c*16 + l15]  (per-lane float4 -> ds_read_b128)
  __shared__ float hrT[MCHUNK][64];   // 16 KB
  // xr_s[ms] = {xrC0, xrC1, xrC2, srC, rp0, rp1, rp2, pad}
  __shared__ float xr_s[MCHUNK][8];   // 2 KB

  const int tid  = threadIdx.x;
  const int wave = tid >> 6;          // 0..7
  const int lane = tid & 63;
  const int l15  = lane & 15;
  const int quad = lane >> 4;

  const int nblk   = blockIdx.x / MSPLIT;
  const int msplit = blockIdx.x % MSPLIT;
  const int n0     = nblk * NBLOCK + wave * 16;
  const int mBase  = msplit * MCHUNK;

  // per-lane A-row n
  const int nA = n0 + l15;
  const float xl0 = x_l[nA * 3 + 0];
  const float xl1 = x_l[nA * 3 + 1];
  const float xl2 = x_l[nA * 3 + 2];
  const float slC = fmaf(xl2, xl2, fmaf(xl1, xl1, xl0 * xl0)) * C1E;
  const float lp0 = h_l[nA * 64 + 61];
  const float lp1 = h_l[nA * 64 + 62];
  const float lp2 = h_l[nA * 64 + 63];

  // layer-1 weights as f32 pairs over j (this lane's 16 h1 cols:
  // h1 = quad*8 + j for j<8, 32 + quad*8 + (j-8) for j>=8)
  f32x2 w1d2[8], w1h2[8], w1y2[8], b1p2[8];
#pragma unroll
  for (int p = 0; p < 8; ++p) {
    const int j0 = 2 * p, j1 = 2 * p + 1;
    const int hA = (j0 < 8) ? (quad * 8 + j0) : (32 + quad * 8 + (j0 - 8));
    const int hB = (j1 < 8) ? (quad * 8 + j1) : (32 + quad * 8 + (j1 - 8));
    w1d2[p] = f32x2{W1[0 * 64 + hA], W1[0 * 64 + hB]};
    w1h2[p] = f32x2{W1[1 * 64 + hA], W1[1 * 64 + hB]};
    w1y2[p] = f32x2{W1[2 * 64 + hA], W1[2 * 64 + hB]};
    // edge_raw[3] == 1 -> fold W1 row 3 into bias
    b1p2[p] = f32x2{b1[hA] + W1[3 * 64 + hA], b1[hB] + W1[3 * 64 + hB]};
  }

  // W2 B-frags (f16): B[k = half*32 + quad*8 + j][col = c*16 + l15]
  f16x8 Bfrag[4][2];
#pragma unroll
  for (int c = 0; c < 4; ++c) {
#pragma unroll
    for (int h = 0; h < 2; ++h) {
      f16x8 f;
#pragma unroll
      for (int j = 0; j < 8; ++j) {
        const int k = h * 32 + quad * 8 + j;
        f[j] = (_Float16)W2[k * 64 + c * 16 + l15];
      }
      Bfrag[c][h] = f;
    }
  }

  // b2 folded into sigmoid exp-arg: arg = e*NL2E + NL2E*b2[h2]
  f32x2 b2c2[4];
#pragma unroll
  for (int c = 0; c < 4; ++c) {
    const float v = NL2E * b2[c * 16 + l15];
    b2c2[c] = f32x2{v, v};
  }

  // stage h_r chunk (transposed groups of 4) + precomputed xr terms
  for (int idx = tid; idx < MCHUNK * 64; idx += BLOCKT) {
    const int mm = idx >> 6, w = idx & 63;
    const int i = w >> 2, c = w & 3;
    hrT[mm][w] = h_r[(mBase + mm) * 64 + c * 16 + i];
  }
  if (tid < MCHUNK) {
    const int m = mBase + tid;
    const float a0 = x_r[m * 3 + 0], a1 = x_r[m * 3 + 1], a2 = x_r[m * 3 + 2];
    const float r0 = h_r[m * 64 + 61], r1 = h_r[m * 64 + 62], r2 = h_r[m * 64 + 63];
    xr_s[tid][0] = a0 * (-2.0f * C1E);
    xr_s[tid][1] = a1 * (-2.0f * C1E);
    xr_s[tid][2] = a2 * (-2.0f * C1E);
    xr_s[tid][3] = fmaf(a2, a2, fmaf(a1, a1, a0 * a0)) * C1E;
    xr_s[tid][4] = r0;
    xr_s[tid][5] = r1;
    xr_s[tid][6] = r2;
    xr_s[tid][7] = 0.f;
  }

  const f32x4 zero4 = {0.f, 0.f, 0.f, 0.f};
  const f32x2 one2 = {1.f, 1.f};
  const f32x2 nl2e2 = {NL2E, NL2E};
  f32x2 numr2[4][2], denr2[4][2];
#pragma unroll
  for (int c = 0; c < 4; ++c)
#pragma unroll
    for (int h = 0; h < 2; ++h) {
      numr2[c][h] = f32x2{0.f, 0.f};
      denr2[c][h] = f32x2{0.f, 0.f};
    }

  __syncthreads();

#pragma unroll 2
  for (int ms = 0; ms < MCHUNK; ++ms) {
    // dist = exp2(C1E*(|xl|^2 + |xr|^2 - 2 xl.xr))
    const f32x4 xa = *(const f32x4*)&xr_s[ms][0];   // xrC0 xrC1 xrC2 srC
    const f32x4 xb = *(const f32x4*)&xr_s[ms][4];   // rp0 rp1 rp2 pad
    const float arg = fmaf(xl0, xa[0], fmaf(xl1, xa[1], fmaf(xl2, xa[2], slC + xa[3])));
    const float dist = fast_exp2(arg);
    const float hb = fmaf(lp0, xb[1], lp1 * xb[0]);
    const float hy = lp2 * xb[2];
    const f32x2 distv = {dist, dist};
    const f32x2 hbv = {hb, hb};
    const f32x2 hyv = {hy, hy};

    // layer 1 + silu, packed f32, A-frag element order
    f32x2 s2[8];
#pragma unroll
    for (int p = 0; p < 8; ++p) {
      const f32x2 t2 = pk_fma(distv, w1d2[p],
                       pk_fma(hbv, w1h2[p],
                       pk_fma(hyv, w1y2[p], b1p2[p])));
      const f32x2 a2 = t2 * nl2e2;
      f32x2 e2;
      e2.x = fast_exp2(a2.x);
      e2.y = fast_exp2(a2.y);
      const f32x2 dd = e2 + one2;
      f32x2 r2;
      r2.x = fast_rcp(dd.x);
      r2.y = fast_rcp(dd.y);
      s2[p] = t2 * r2;                 // silu = t/(1+2^(t*NL2E)); inf->0 tail OK
    }
    i32x4 p0, p1;
    p0.x = pack_f16_rtz(s2[0].x, s2[0].y);  p0.y = pack_f16_rtz(s2[1].x, s2[1].y);
    p0.z = pack_f16_rtz(s2[2].x, s2[2].y);  p0.w = pack_f16_rtz(s2[3].x, s2[3].y);
    p1.x = pack_f16_rtz(s2[4].x, s2[4].y);  p1.y = pack_f16_rtz(s2[5].x, s2[5].y);
    p1.z = pack_f16_rtz(s2[6].x, s2[6].y);  p1.w = pack_f16_rtz(s2[7].x, s2[7].y);
    const f16x8 A0 = __builtin_bit_cast(f16x8, p0);
    const f16x8 A1 = __builtin_bit_cast(f16x8, p1);

    f32x4 acc[4];
#pragma unroll
    for (int c = 0; c < 4; ++c) {
      acc[c] = __builtin_amdgcn_mfma_f32_16x16x32_f16(A0, Bfrag[c][0], zero4, 0, 0, 0);
      acc[c] = __builtin_amdgcn_mfma_f32_16x16x32_f16(A1, Bfrag[c][1], acc[c], 0, 0, 0);
    }

    // sigmoid + accumulate (f32, r-pairs packed).
    const f32x4 hrv4 = *(const f32x4*)&hrT[ms][l15 * 4];
#pragma unroll
    for (int c = 0; c < 4; ++c) {
      const f32x2 hrv2 = {hrv4[c], hrv4[c]};
#pragma unroll
      for (int h = 0; h < 2; ++h) {
        const f32x2 a2 = {acc[c][2 * h], acc[c][2 * h + 1]};
        const f32x2 arg2 = pk_fma(a2, nl2e2, b2c2[c]);
        f32x2 e2;
        e2.x = fast_exp2(arg2.x);
        e2.y = fast_exp2(arg2.y);
        const f32x2 dden = e2 + one2;
        f32x2 w2;
        w2.x = fast_rcp(dden.x);
        w2.y = fast_rcp(dden.y);
        numr2[c][h] = pk_fma(w2, hrv2, numr2[c][h]);
        denr2[c][h] = denr2[c][h] + w2;
      }
    }
  }

#pragma unroll
  for (int c = 0; c < 4; ++c)
#pragma unroll
    for (int h = 0; h < 2; ++h)
#pragma unroll
      for (int k = 0; k < 2; ++k) {
        const int r = 2 * h + k;
        const int n = n0 + quad * 4 + r;
        const int h2 = c * 16 + l15;
        atomicAdd(&num_g[n * 64 + h2], k ? numr2[c][h].y : numr2[c][h].x);
        atomicAdd(&den_g[n * 64 + h2], k ? denr2[c][h].y : denr2[c][h].x);
      }
}

// ---------------------------------------------------------------------------
// Node phase: NODE_ROWS rows per block (wave-local, no inner barriers).
// h_agg = num/(den+1e-6); z = cat(h_l,h_agg)@Wn1 + bn1 -> LN -> silu ->
// @Wn2 + bn2; out = h_l + z. Grid: NTOT/NODE_ROWS blocks of 256.
// ---------------------------------------------------------------------------
__global__ __launch_bounds__(256)
void node_kernel(const float* __restrict__ h_l,
                 const float* __restrict__ num_g,
                 const float* __restrict__ den_g,
                 const float* __restrict__ Wn1,
                 const float* __restrict__ bn1,
                 const float* __restrict__ ln_g,
                 const float* __restrict__ ln_b,
                 const float* __restrict__ Wn2,
                 const float* __restrict__ bn2,
                 float* __restrict__ out) {
  __shared__ float Wn1_s[128 * 64];
  __shared__ float Wn2_s[64 * 64];
  __shared__ float xbuf[4][128];
  __shared__ float zbuf[4][64];

  const int tid = threadIdx.x;
  for (int i = tid; i < 128 * 64; i += 256) Wn1_s[i] = Wn1[i];
  for (int i = tid; i < 64 * 64; i += 256) Wn2_s[i] = Wn2[i];

  const int wave = tid >> 6, lane = tid & 63;

  __syncthreads();

#pragma unroll 1
  for (int it = 0; it < NODE_ROWS / 4; ++it) {
    const int row = blockIdx.x * NODE_ROWS + it * 4 + wave;

    const float hl = h_l[row * 64 + lane];
    const float dn = den_g[row * 64 + lane] + 1e-6f;
    const float hagg = num_g[row * 64 + lane] * fast_rcp(dn);
    xbuf[wave][lane] = hl;
    xbuf[wave][64 + lane] = hagg;

    float t = bn1[lane];
#pragma unroll 8
    for (int k = 0; k < 128; ++k) t = fmaf(xbuf[wave][k], Wn1_s[k * 64 + lane], t);

    float s1 = t, s2 = t * t;
#pragma unroll
    for (int off = 32; off; off >>= 1) {
      s1 += __shfl_xor(s1, off);
      s2 += __shfl_xor(s2, off);
    }
    const float mu = s1 * 0.015625f;
    const float var = fmaf(s2, 0.015625f, -mu * mu);
    const float rs = fast_rsq(var + 1e-5f);
    const float zn = fmaf((t - mu) * rs, ln_g[lane], ln_b[lane]);
    const float sz = zn * fast_rcp(1.0f + fast_exp2(zn * NL2E));  // silu
    zbuf[wave][lane] = sz;

    float o = bn2[lane];
#pragma unroll 8
    for (int k = 0; k < 64; ++k) o = fmaf(zbuf[wave][k], Wn2_s[k * 64 + lane], o);

    out[row * 64 + lane] = hl + o;
  }
}

extern "C" void kernel_launch(void* const* d_in, const int* in_sizes, int n_in,
                              void* d_out, int out_size, void* d_ws, size_t ws_size,
                              hipStream_t stream) {
  const float* h_l = (const float*)d_in[0];
  const float* x_l = (const float*)d_in[1];
  const float* h_r = (const float*)d_in[2];
  const float* x_r = (const float*)d_in[3];
  const float* W1  = (const float*)d_in[4];
  const float* b1  = (const float*)d_in[5];
  const float* W2  = (const float*)d_in[6];
  const float* b2  = (const float*)d_in[7];
  const float* Wn1 = (const float*)d_in[8];
  const float* bn1 = (const float*)d_in[9];
  const float* lng = (const float*)d_in[10];
  const float* lnb = (const float*)d_in[11];
  const float* Wn2 = (const float*)d_in[12];
  const float* bn2 = (const float*)d_in[13];

  float* num_g = (float*)d_ws;
  float* den_g = num_g + (size_t)NTOT * 64;

  hipMemsetAsync(d_ws, 0, (size_t)NTOT * 64 * 2 * sizeof(float), stream);
  edge_kernel<<<dim3((NTOT / NBLOCK) * MSPLIT), dim3(BLOCKT), 0, stream>>>(
      h_l, x_l, h_r, x_r, W1, b1, W2, b2, num_g, den_g);
  node_kernel<<<dim3(NTOT / NODE_ROWS), dim3(256), 0, stream>>>(
      h_l, num_g, den_g, Wn1, bn1, lng, lnb, Wn2, bn2, (float*)d_out);
}

// Round 18
// 212.692 us; speedup vs baseline: 1.0337x; 1.0337x over previous
//
#include <hip/hip_runtime.h>
#include <hip/hip_bf16.h>
#include <hip/hip_fp16.h>

// INPUTS/OUTPUT ARE FLOAT32 (R1/R3/R4 NaN'd reading them as bf16).
// FINAL CONFIG (best measured: R16, 212.7 us total / 145.3 us edge).
// PERF NOTES (session summary):
//  - R5: forced low VGPR budget -> scratch spills, 2.6x slower. Keep (256,2).
//  - R11/R13/R16: three different inner-loop mixes all = ~145.5 us edge ->
//    instruction floor; kernel is trans-pipe bound (~1.08G transcendental
//    lane-ops, algorithm-intrinsic; ~80% of trans roofline).
//  - Occupancy levers ALL exhausted: bounds(2/4/none), grid x2, LDS /2,
//    weights->LDS, 512-thread blocks — none raise real residency; cap is
//    per-wave register footprint.
//  - Node/memset/launch overhead (~67 us) invariant to node restructure.

#define NTOT 2048
#define MTOT 2048
#define MSPLIT 32
#define MCHUNK 64   // == per-block m range: single staging chunk
#define NODE_ROWS 4 // rows per node block (1 per wave)

typedef _Float16 f16x8 __attribute__((ext_vector_type(8)));
typedef float f32x4  __attribute__((ext_vector_type(4)));
typedef float f32x2  __attribute__((ext_vector_type(2)));
typedef int   i32x4  __attribute__((ext_vector_type(4)));

// exp(x) = 2^(x*log2e); sigmoid(x) = 1/(1+2^(-x*log2e))
#define NL2E (-1.4426950408889634f)
// exp(-d2/5) = 2^(d2 * -log2e/5)
#define C1E  (-0.2885390081777927f)

__device__ __forceinline__ float fast_exp2(float x) {
#if __has_builtin(__builtin_amdgcn_exp2f)
  return __builtin_amdgcn_exp2f(x);
#else
  return __exp2f(x);
#endif
}
__device__ __forceinline__ float fast_rcp(float x) {
#if __has_builtin(__builtin_amdgcn_rcpf)
  return __builtin_amdgcn_rcpf(x);
#else
  return 1.0f / x;
#endif
}
__device__ __forceinline__ float fast_rsq(float x) {
#if __has_builtin(__builtin_amdgcn_rsqf)
  return __builtin_amdgcn_rsqf(x);
#else
  return rsqrtf(x);
#endif
}
__device__ __forceinline__ f32x2 pk_fma(f32x2 a, f32x2 b, f32x2 c) {
  return __builtin_elementwise_fma(a, b, c);
}

// pack two f32 -> two f16 (RTZ) in one u32 via v_cvt_pkrtz_f16_f32 (1 instr).
__device__ __forceinline__ unsigned pack_f16_rtz(float lo, float hi) {
#if __has_builtin(__builtin_amdgcn_cvt_pkrtz)
  auto p = __builtin_amdgcn_cvt_pkrtz(lo, hi);  // __fp16 ext_vector(2)
  return __builtin_bit_cast(unsigned, p);
#else
  union { _Float16 h; unsigned short u; } a, b;
  a.h = (_Float16)lo; b.h = (_Float16)hi;
  return (unsigned)a.u | ((unsigned)b.u << 16);
#endif
}

// ---------------------------------------------------------------------------
// Edge phase: per wave, 16 n-rows; loop over this block's 64-m range.
// dist-arg via d2 expansion (4 slots); layer1+silu in packed f32; A-frags
// packed with cvt_pkrtz; mfma_16x16x32_f16; sigmoid f32; atomicAdd partials.
// Grid: (NTOT/64) * MSPLIT = 1024 blocks of 256.
// ---------------------------------------------------------------------------
__global__ __launch_bounds__(256, 2)
void edge_kernel(const float* __restrict__ h_l,
                 const float* __restrict__ x_l,
                 const float* __restrict__ h_r,
                 const float* __restrict__ x_r,
                 const float* __restrict__ W1,
                 const float* __restrict__ b1,
                 const float* __restrict__ W2,
                 const float* __restrict__ b2,
                 float* __restrict__ num_g,
                 float* __restrict__ den_g) {
  // hrT[ms][l15*4 + c] = h_r[m][c*16 + l15]  (per-lane float4 -> ds_read_b128)
  __shared__ float hrT[MCHUNK][64];   // 16 KB
  // xr_s[ms] = {xrC0, xrC1, xrC2, srC, rp0, rp1, rp2, pad}
  //   xrC = x_r * (-2*C1E), srC = |x_r|^2 * C1E
  __shared__ float xr_s[MCHUNK][8];   // 2 KB

  const int tid  = threadIdx.x;
  const int wave = tid >> 6;
  const int lane = tid & 63;
  const int l15  = lane & 15;
  const int quad = lane >> 4;

  const int nblk   = blockIdx.x / MSPLIT;
  const int msplit = blockIdx.x % MSPLIT;
  const int n0     = nblk * 64 + wave * 16;
  const int mBase  = msplit * MCHUNK;

  // per-lane A-row n
  const int nA = n0 + l15;
  const float xl0 = x_l[nA * 3 + 0];
  const float xl1 = x_l[nA * 3 + 1];
  const float xl2 = x_l[nA * 3 + 2];
  const float slC = fmaf(xl2, xl2, fmaf(xl1, xl1, xl0 * xl0)) * C1E;
  const float lp0 = h_l[nA * 64 + 61];
  const float lp1 = h_l[nA * 64 + 62];
  const float lp2 = h_l[nA * 64 + 63];

  // layer-1 weights as f32 pairs over j (this lane's 16 h1 cols:
  // h1 = quad*8 + j for j<8, 32 + quad*8 + (j-8) for j>=8)
  f32x2 w1d2[8], w1h2[8], w1y2[8], b1p2[8];
#pragma unroll
  for (int p = 0; p < 8; ++p) {
    const int j0 = 2 * p, j1 = 2 * p + 1;
    const int hA = (j0 < 8) ? (quad * 8 + j0) : (32 + quad * 8 + (j0 - 8));
    const int hB = (j1 < 8) ? (quad * 8 + j1) : (32 + quad * 8 + (j1 - 8));
    w1d2[p] = f32x2{W1[0 * 64 + hA], W1[0 * 64 + hB]};
    w1h2[p] = f32x2{W1[1 * 64 + hA], W1[1 * 64 + hB]};
    w1y2[p] = f32x2{W1[2 * 64 + hA], W1[2 * 64 + hB]};
    // edge_raw[3] == 1 -> fold W1 row 3 into bias
    b1p2[p] = f32x2{b1[hA] + W1[3 * 64 + hA], b1[hB] + W1[3 * 64 + hB]};
  }

  // W2 B-frags (f16): B[k = half*32 + quad*8 + j][col = c*16 + l15]
  f16x8 Bfrag[4][2];
#pragma unroll
  for (int c = 0; c < 4; ++c) {
#pragma unroll
    for (int h = 0; h < 2; ++h) {
      f16x8 f;
#pragma unroll
      for (int j = 0; j < 8; ++j) {
        const int k = h * 32 + quad * 8 + j;
        f[j] = (_Float16)W2[k * 64 + c * 16 + l15];
      }
      Bfrag[c][h] = f;
    }
  }

  // b2 folded into sigmoid exp-arg: arg = e*NL2E + NL2E*b2[h2]
  f32x2 b2c2[4];
#pragma unroll
  for (int c = 0; c < 4; ++c) {
    const float v = NL2E * b2[c * 16 + l15];
    b2c2[c] = f32x2{v, v};
  }

  // stage h_r chunk (transposed groups of 4) + precomputed xr terms
  for (int idx = tid; idx < MCHUNK * 64; idx += 256) {
    const int mm = idx >> 6, w = idx & 63;
    const int i = w >> 2, c = w & 3;
    hrT[mm][w] = h_r[(mBase + mm) * 64 + c * 16 + i];
  }
  if (tid < MCHUNK) {
    const int m = mBase + tid;
    const float a0 = x_r[m * 3 + 0], a1 = x_r[m * 3 + 1], a2 = x_r[m * 3 + 2];
    const float r0 = h_r[m * 64 + 61], r1 = h_r[m * 64 + 62], r2 = h_r[m * 64 + 63];
    xr_s[tid][0] = a0 * (-2.0f * C1E);
    xr_s[tid][1] = a1 * (-2.0f * C1E);
    xr_s[tid][2] = a2 * (-2.0f * C1E);
    xr_s[tid][3] = fmaf(a2, a2, fmaf(a1, a1, a0 * a0)) * C1E;
    xr_s[tid][4] = r0;
    xr_s[tid][5] = r1;
    xr_s[tid][6] = r2;
    xr_s[tid][7] = 0.f;
  }

  const f32x4 zero4 = {0.f, 0.f, 0.f, 0.f};
  const f32x2 one2 = {1.f, 1.f};
  const f32x2 nl2e2 = {NL2E, NL2E};
  f32x2 numr2[4][2], denr2[4][2];
#pragma unroll
  for (int c = 0; c < 4; ++c)
#pragma unroll
    for (int h = 0; h < 2; ++h) {
      numr2[c][h] = f32x2{0.f, 0.f};
      denr2[c][h] = f32x2{0.f, 0.f};
    }

  __syncthreads();

#pragma unroll 2
  for (int ms = 0; ms < MCHUNK; ++ms) {
    // dist = exp2(C1E*(|xl|^2 + |xr|^2 - 2 xl.xr)) — 4 slots + exp
    const f32x4 xa = *(const f32x4*)&xr_s[ms][0];   // xrC0 xrC1 xrC2 srC
    const f32x4 xb = *(const f32x4*)&xr_s[ms][4];   // rp0 rp1 rp2 pad
    const float arg = fmaf(xl0, xa[0], fmaf(xl1, xa[1], fmaf(xl2, xa[2], slC + xa[3])));
    const float dist = fast_exp2(arg);
    const float hb = fmaf(lp0, xb[1], lp1 * xb[0]);
    const float hy = lp2 * xb[2];
    const f32x2 distv = {dist, dist};
    const f32x2 hbv = {hb, hb};
    const f32x2 hyv = {hy, hy};

    // layer 1 + silu, packed f32 (native pipes), A-frag element order
    f32x2 s2[8];
#pragma unroll
    for (int p = 0; p < 8; ++p) {
      const f32x2 t2 = pk_fma(distv, w1d2[p],
                       pk_fma(hbv, w1h2[p],
                       pk_fma(hyv, w1y2[p], b1p2[p])));
      const f32x2 a2 = t2 * nl2e2;
      f32x2 e2;
      e2.x = fast_exp2(a2.x);
      e2.y = fast_exp2(a2.y);
      const f32x2 dd = e2 + one2;
      f32x2 r2;
      r2.x = fast_rcp(dd.x);
      r2.y = fast_rcp(dd.y);
      s2[p] = t2 * r2;                 // silu = t/(1+2^(t*NL2E)); inf->0 tail OK
    }
    i32x4 p0, p1;
    p0.x = pack_f16_rtz(s2[0].x, s2[0].y);  p0.y = pack_f16_rtz(s2[1].x, s2[1].y);
    p0.z = pack_f16_rtz(s2[2].x, s2[2].y);  p0.w = pack_f16_rtz(s2[3].x, s2[3].y);
    p1.x = pack_f16_rtz(s2[4].x, s2[4].y);  p1.y = pack_f16_rtz(s2[5].x, s2[5].y);
    p1.z = pack_f16_rtz(s2[6].x, s2[6].y);  p1.w = pack_f16_rtz(s2[7].x, s2[7].y);
    const f16x8 A0 = __builtin_bit_cast(f16x8, p0);
    const f16x8 A1 = __builtin_bit_cast(f16x8, p1);

    f32x4 acc[4];
#pragma unroll
    for (int c = 0; c < 4; ++c) {
      acc[c] = __builtin_amdgcn_mfma_f32_16x16x32_f16(A0, Bfrag[c][0], zero4, 0, 0, 0);
      acc[c] = __builtin_amdgcn_mfma_f32_16x16x32_f16(A1, Bfrag[c][1], acc[c], 0, 0, 0);
    }

    // sigmoid + accumulate (f32, r-pairs packed).
    // lane holds e[n = n0+quad*4+r][h2 = c*16+l15]; hrv per c via one b128.
    const f32x4 hrv4 = *(const f32x4*)&hrT[ms][l15 * 4];
#pragma unroll
    for (int c = 0; c < 4; ++c) {
      const f32x2 hrv2 = {hrv4[c], hrv4[c]};
#pragma unroll
      for (int h = 0; h < 2; ++h) {
        const f32x2 a2 = {acc[c][2 * h], acc[c][2 * h + 1]};
        const f32x2 arg2 = pk_fma(a2, nl2e2, b2c2[c]);
        f32x2 e2;
        e2.x = fast_exp2(arg2.x);
        e2.y = fast_exp2(arg2.y);
        const f32x2 dden = e2 + one2;
        f32x2 w2;
        w2.x = fast_rcp(dden.x);
        w2.y = fast_rcp(dden.y);
        numr2[c][h] = pk_fma(w2, hrv2, numr2[c][h]);
        denr2[c][h] = denr2[c][h] + w2;
      }
    }
  }

#pragma unroll
  for (int c = 0; c < 4; ++c)
#pragma unroll
    for (int h = 0; h < 2; ++h)
#pragma unroll
      for (int k = 0; k < 2; ++k) {
        const int r = 2 * h + k;
        const int n = n0 + quad * 4 + r;
        const int h2 = c * 16 + l15;
        atomicAdd(&num_g[n * 64 + h2], k ? numr2[c][h].y : numr2[c][h].x);
        atomicAdd(&den_g[n * 64 + h2], k ? denr2[c][h].y : denr2[c][h].x);
      }
}

// ---------------------------------------------------------------------------
// Node phase: NODE_ROWS rows per block (wave-local, no inner barriers).
// h_agg = num/(den+1e-6); z = cat(h_l,h_agg)@Wn1 + bn1 -> LN -> silu ->
// @Wn2 + bn2; out = h_l + z. Grid: NTOT/NODE_ROWS blocks of 256.
// ---------------------------------------------------------------------------
__global__ __launch_bounds__(256)
void node_kernel(const float* __restrict__ h_l,
                 const float* __restrict__ num_g,
                 const float* __restrict__ den_g,
                 const float* __restrict__ Wn1,
                 const float* __restrict__ bn1,
                 const float* __restrict__ ln_g,
                 const float* __restrict__ ln_b,
                 const float* __restrict__ Wn2,
                 const float* __restrict__ bn2,
                 float* __restrict__ out) {
  __shared__ float Wn1_s[128 * 64];
  __shared__ float Wn2_s[64 * 64];
  __shared__ float xbuf[4][128];
  __shared__ float zbuf[4][64];

  const int tid = threadIdx.x;
  for (int i = tid; i < 128 * 64; i += 256) Wn1_s[i] = Wn1[i];
  for (int i = tid; i < 64 * 64; i += 256) Wn2_s[i] = Wn2[i];

  const int wave = tid >> 6, lane = tid & 63;

  __syncthreads();

#pragma unroll 1
  for (int it = 0; it < NODE_ROWS / 4; ++it) {
    const int row = blockIdx.x * NODE_ROWS + it * 4 + wave;

    const float hl = h_l[row * 64 + lane];
    const float dn = den_g[row * 64 + lane] + 1e-6f;
    const float hagg = num_g[row * 64 + lane] * fast_rcp(dn);
    xbuf[wave][lane] = hl;
    xbuf[wave][64 + lane] = hagg;

    float t = bn1[lane];
#pragma unroll 8
    for (int k = 0; k < 128; ++k) t = fmaf(xbuf[wave][k], Wn1_s[k * 64 + lane], t);

    float s1 = t, s2 = t * t;
#pragma unroll
    for (int off = 32; off; off >>= 1) {
      s1 += __shfl_xor(s1, off);
      s2 += __shfl_xor(s2, off);
    }
    const float mu = s1 * 0.015625f;
    const float var = fmaf(s2, 0.015625f, -mu * mu);
    const float rs = fast_rsq(var + 1e-5f);
    const float zn = fmaf((t - mu) * rs, ln_g[lane], ln_b[lane]);
    const float sz = zn * fast_rcp(1.0f + fast_exp2(zn * NL2E));  // silu
    zbuf[wave][lane] = sz;

    float o = bn2[lane];
#pragma unroll 8
    for (int k = 0; k < 64; ++k) o = fmaf(zbuf[wave][k], Wn2_s[k * 64 + lane], o);

    out[row * 64 + lane] = hl + o;
  }
}

extern "C" void kernel_launch(void* const* d_in, const int* in_sizes, int n_in,
                              void* d_out, int out_size, void* d_ws, size_t ws_size,
                              hipStream_t stream) {
  const float* h_l = (const float*)d_in[0];
  const float* x_l = (const float*)d_in[1];
  const float* h_r = (const float*)d_in[2];
  const float* x_r = (const float*)d_in[3];
  const float* W1  = (const float*)d_in[4];
  const float* b1  = (const float*)d_in[5];
  const float* W2  = (const float*)d_in[6];
  const float* b2  = (const float*)d_in[7];
  const float* Wn1 = (const float*)d_in[8];
  const float* bn1 = (const float*)d_in[9];
  const float* lng = (const float*)d_in[10];
  const float* lnb = (const float*)d_in[11];
  const float* Wn2 = (const float*)d_in[12];
  const float* bn2 = (const float*)d_in[13];

  float* num_g = (float*)d_ws;
  float* den_g = num_g + (size_t)NTOT * 64;

  hipMemsetAsync(d_ws, 0, (size_t)NTOT * 64 * 2 * sizeof(float), stream);
  edge_kernel<<<dim3((NTOT / 64) * MSPLIT), dim3(256), 0, stream>>>(
      h_l, x_l, h_r, x_r, W1, b1, W2, b2, num_g, den_g);
  node_kernel<<<dim3(NTOT / NODE_ROWS), dim3(256), 0, stream>>>(
      h_l, num_g, den_g, Wn1, bn1, lng, lnb, Wn2, bn2, (float*)d_out);
}